// Round 8
// baseline (454.164 us; speedup 1.0000x reference)
//
#include <hip/hip_runtime.h>
#include <hip/hip_bf16.h>

#define E_ 8
#define D_ 1024
#define F_ 4096
#define S_ 2048
#define B_ 2
#define T_ 4096
#define CAP 1024
#define LN_EPS 1e-5f
#define NTABF 2048

typedef __attribute__((ext_vector_type(8))) short short8;
typedef __attribute__((ext_vector_type(4))) float f32x4;

__device__ __forceinline__ unsigned short f2bf(float f) {
  __hip_bfloat16 h = __float2bfloat16(f);
  return *reinterpret_cast<unsigned short*>(&h);
}

__device__ __forceinline__ void gload_lds16(const void* g, void* l) {
  __builtin_amdgcn_global_load_lds((const __attribute__((address_space(1))) void*)g,
                                   (__attribute__((address_space(3))) void*)l,
                                   16, 0, 0);
}

// ---------- fused gating + LN + bucket scatter + out init (x + b2[e]) ----------
__global__ __launch_bounds__(256) void gate_ln_kernel(
    const float* __restrict__ x, const float* __restrict__ cent,
    const float* __restrict__ g_, const float* __restrict__ bb_,
    const float* __restrict__ b2_,
    int* __restrict__ counts, int* __restrict__ perm,
    unsigned short* __restrict__ Xb, float* __restrict__ outp) {
  int token = blockIdx.x * 4 + (threadIdx.x >> 6);
  int lane = threadIdx.x & 63;
  int s = token & (S_ - 1), b = token >> 11;
  const float* xr = x + ((size_t)s * B_ + b) * D_;
  float* orow = outp + ((size_t)s * B_ + b) * D_;

  float v[16];
  float acc[E_];
#pragma unroll
  for (int e = 0; e < E_; ++e) acc[e] = 0.f;
  float sum = 0.f, sq = 0.f;
#pragma unroll
  for (int c = 0; c < 4; ++c) {
    f32x4 xv = *(const f32x4*)(xr + c * 256 + lane * 4);
    v[c * 4 + 0] = xv.x; v[c * 4 + 1] = xv.y; v[c * 4 + 2] = xv.z; v[c * 4 + 3] = xv.w;
    sum += xv.x + xv.y + xv.z + xv.w;
    sq += xv.x * xv.x + xv.y * xv.y + xv.z * xv.z + xv.w * xv.w;
#pragma unroll
    for (int e = 0; e < E_; ++e) {
      f32x4 cv = *(const f32x4*)(cent + e * D_ + c * 256 + lane * 4);
      acc[e] += xv.x * cv.x + xv.y * cv.y + xv.z * cv.z + xv.w * cv.w;
    }
  }
#pragma unroll
  for (int off = 32; off > 0; off >>= 1) {
    sum += __shfl_down(sum, off);
    sq += __shfl_down(sq, off);
#pragma unroll
    for (int e = 0; e < E_; ++e) acc[e] += __shfl_down(acc[e], off);
  }
  int best = 0, slot = 0;
  if (lane == 0) {
    float bv = acc[0];
#pragma unroll
    for (int e = 1; e < E_; ++e) if (acc[e] > bv) { bv = acc[e]; best = e; }
    slot = atomicAdd(&counts[best], 1);
    perm[best * CAP + slot] = token;
  }
  best = __shfl(best, 0); slot = __shfl(slot, 0);
  sum = __shfl(sum, 0); sq = __shfl(sq, 0);
  float mu = sum * (1.f / D_);
  float var = sq * (1.f / D_) - mu * mu;
  float rstd = rsqrtf(var + LN_EPS);
  int e = best;
  unsigned short* dst = Xb + (size_t)(e * CAP + slot) * D_;
#pragma unroll
  for (int c = 0; c < 4; ++c) {
    int d = c * 256 + lane * 4;
    f32x4 gv = *(const f32x4*)(g_ + e * D_ + d);
    f32x4 bv = *(const f32x4*)(bb_ + e * D_ + d);
    f32x4 b2v = *(const f32x4*)(b2_ + e * D_ + d);
    ushort4 o;
    o.x = f2bf((v[c * 4 + 0] - mu) * rstd * gv.x + bv.x);
    o.y = f2bf((v[c * 4 + 1] - mu) * rstd * gv.y + bv.y);
    o.z = f2bf((v[c * 4 + 2] - mu) * rstd * gv.z + bv.z);
    o.w = f2bf((v[c * 4 + 3] - mu) * rstd * gv.w + bv.w);
    *(ushort4*)(dst + d) = o;
    f32x4 oi;
    oi.x = v[c * 4 + 0] + b2v.x; oi.y = v[c * 4 + 1] + b2v.y;
    oi.z = v[c * 4 + 2] + b2v.z; oi.w = v[c * 4 + 3] + b2v.w;
    *(f32x4*)(orow + d) = oi;
  }
}

// ---------- prefix + XCD-grouped flat schedule tables ----------
__global__ __launch_bounds__(256) void prefix_kernel(
    const int* __restrict__ counts, int* __restrict__ offs,
    int* __restrict__ tabF1, int* __restrict__ tabF2) {
  __shared__ int q[8][256];
  __shared__ int ql[8];
  __shared__ int nb[E_];
  const int tid = threadIdx.x;
  if (tid == 0) {
    int s = 0;
    for (int e = 0; e < E_; ++e) {
      offs[e] = s;
      nb[e] = (counts[e] + 127) >> 7;
      s += counts[e];
    }
    offs[E_] = s;
    for (int x = 0; x < 8; ++x) ql[x] = 0;
    int g = 0;
    for (int n = 0; n < F_ / 128; ++n)
      for (int e = 0; e < E_; ++e) {
        int x = g & 7; ++g;
        for (int m = 0; m < nb[e]; ++m) q[x][ql[x]++] = (e << 24) | (m << 16) | (n << 8);
      }
  }
  __syncthreads();
  for (int i = tid; i < NTABF; i += 256) {
    int p = i >> 3, x = i & 7;
    tabF1[i] = (p < ql[x]) ? q[x][p] : -1;
  }
  __syncthreads();
  if (tid == 0) {
    for (int x = 0; x < 8; ++x) ql[x] = 0;
    int g = 0;
    for (int kz = 0; kz < 4; ++kz)
      for (int n = 0; n < D_ / 128; ++n)
        for (int e = 0; e < E_; ++e) {
          int x = g & 7; ++g;
          for (int m = 0; m < nb[e]; ++m)
            q[x][ql[x]++] = (e << 24) | (m << 16) | (n << 8) | kz;
        }
  }
  __syncthreads();
  for (int i = tid; i < NTABF; i += 256) {
    int p = i >> 3, x = i & 7;
    tabF2[i] = (p < ql[x]) ? q[x][p] : -1;
  }
}

// ---------- transpose + fp32->bf16: in [E][R][C] -> out [E][C][R] ----------
__global__ __launch_bounds__(256) void transpose_bf16_kernel(const float* __restrict__ in,
    unsigned short* __restrict__ out, int R, int C) {
  __shared__ float tile[64][65];
  const float* src = in + (size_t)blockIdx.z * R * C;
  unsigned short* dst = out + (size_t)blockIdx.z * R * C;
  int c0 = blockIdx.x * 64, r0 = blockIdx.y * 64;
  int tid = threadIdx.x;
#pragma unroll
  for (int i = 0; i < 4; ++i) {
    int u = i * 256 + tid;
    int rr = u >> 4, c4 = (u & 15) * 4;
    f32x4 vv = *(const f32x4*)(src + (size_t)(r0 + rr) * C + c0 + c4);
    tile[rr][c4 + 0] = vv.x; tile[rr][c4 + 1] = vv.y;
    tile[rr][c4 + 2] = vv.z; tile[rr][c4 + 3] = vv.w;
  }
  __syncthreads();
#pragma unroll
  for (int i = 0; i < 4; ++i) {
    int u = i * 256 + tid;
    int orow = u >> 4;
    int oc4 = (u & 15) * 4;
    ushort4 o;
    o.x = f2bf(tile[oc4 + 0][orow]);
    o.y = f2bf(tile[oc4 + 1][orow]);
    o.z = f2bf(tile[oc4 + 2][orow]);
    o.w = f2bf(tile[oc4 + 3][orow]);
    *(ushort4*)(dst + (size_t)(c0 + orow) * R + r0 + oc4) = o;
  }
}

// ---------- PRIMARY grouped GEMM (m97 structure): A[rows][K] bf16 x BT[E][N][K] bf16 ----
// global_load_lds staging for both operands, single-buffered LDS, 2-barrier loop.
// MODE 0: H = relu(A*W1 + b1) -> bf16 compact   MODE 1: atomicAdd into out (split-K)
template <int K, int N, int MODE, int KSPLIT>
__global__ __launch_bounds__(256) void moe_gemm_bt(
    const unsigned short* __restrict__ A,
    const unsigned short* __restrict__ BT,
    const float* __restrict__ bias,
    const int* __restrict__ counts,
    const int* __restrict__ offs,
    const int* __restrict__ tab,
    const int* __restrict__ perm,
    void* __restrict__ outp) {
  const int te = tab[blockIdx.x];
  if (te < 0) return;
  const int e = te >> 24;
  const int m0 = ((te >> 16) & 255) << 7;
  const int n0 = ((te >> 8) & 255) << 7;
  const int kz = te & 255;
  const int cnt = counts[e];
  const int aoff = (MODE == 0) ? e * CAP : offs[e];
  const int hoff = offs[e];
  const int kstart = kz * (K / KSPLIT);
  constexpr int NSTEP = (K / KSPLIT) / 32;

  const int tid = threadIdx.x;
  const int lane = tid & 63;
  const int wave = tid >> 6;

  // [q 0..3][row/col 0..127][8 bf16]
  __shared__ __align__(16) unsigned short lA[4096];
  __shared__ __align__(16) unsigned short lB[4096];

  // staging cells: thread covers (q0, idx) and (q0+2, idx)
  const int idx = tid & 127;
  const int q0 = tid >> 7;  // 0..1
  const int arow = aoff + min(m0 + idx, cnt - 1);
  const unsigned short* asrc = A + (size_t)arow * K + kstart + q0 * 8;
  const unsigned short* bsrc = BT + ((size_t)e * N + n0 + idx) * K + kstart + q0 * 8;

  char* lAd0 = (char*)lA + wave * 1024;
  char* lAd1 = (char*)lA + wave * 1024 + 4096;
  char* lBd0 = (char*)lB + wave * 1024;
  char* lBd1 = (char*)lB + wave * 1024 + 4096;

  f32x4 acc[4][4] = {};
  const int wr = (wave >> 1) * 64;
  const int wc = (wave & 1) * 64;
  const int fr = lane & 15;
  const int fq = lane >> 4;

  for (int t = 0; t < NSTEP; ++t) {
    const int ko = t * 32;
    gload_lds16(asrc + ko, lAd0);
    gload_lds16(asrc + ko + 16, lAd1);
    gload_lds16(bsrc + ko, lBd0);
    gload_lds16(bsrc + ko + 16, lBd1);
    __syncthreads();
    short8 af[4], bf4[4];
#pragma unroll
    for (int m = 0; m < 4; ++m)
      af[m] = *(const short8*)&lA[fq * 1024 + (wr + m * 16 + fr) * 8];
#pragma unroll
    for (int n = 0; n < 4; ++n)
      bf4[n] = *(const short8*)&lB[fq * 1024 + (wc + n * 16 + fr) * 8];
    __builtin_amdgcn_s_setprio(1);
#pragma unroll
    for (int m = 0; m < 4; ++m) {
#pragma unroll
      for (int n = 0; n < 4; ++n)
        acc[m][n] = __builtin_amdgcn_mfma_f32_16x16x32_bf16(af[m], bf4[n], acc[m][n], 0, 0, 0);
    }
    __builtin_amdgcn_s_setprio(0);
    __syncthreads();
  }

  if (MODE == 0) {
    unsigned short* Hout = (unsigned short*)outp;
    float bv[4];
#pragma unroll
    for (int n = 0; n < 4; ++n) bv[n] = bias[e * N + n0 + wc + n * 16 + fr];
#pragma unroll
    for (int m = 0; m < 4; ++m) {
#pragma unroll
      for (int j = 0; j < 4; ++j) {
        int rg = m0 + wr + m * 16 + fq * 4 + j;
        if (rg < cnt) {
          size_t base = (size_t)(hoff + rg) * N;
#pragma unroll
          for (int n = 0; n < 4; ++n) {
            float hv = acc[m][n][j] + bv[n];
            hv = fmaxf(hv, 0.f);
            Hout[base + n0 + wc + n * 16 + fr] = f2bf(hv);
          }
        }
      }
    }
  } else {
    float* Out = (float*)outp;
#pragma unroll
    for (int m = 0; m < 4; ++m) {
#pragma unroll
      for (int j = 0; j < 4; ++j) {
        int rg = m0 + wr + m * 16 + fq * 4 + j;
        if (rg < cnt) {
          int token = perm[e * CAP + rg];
          size_t base = ((size_t)(token & (S_ - 1)) * B_ + (token >> 11)) * (size_t)D_;
#pragma unroll
          for (int n = 0; n < 4; ++n)
            atomicAdd(&Out[base + n0 + wc + n * 16 + fr], acc[m][n][j]);
        }
      }
    }
  }
}

// ---------- FALLBACK grouped GEMM (R7, fp32 W reg-staged): used when ws is small ----
template <int K, int N, int MODE, int KSPLIT>
__global__ __launch_bounds__(256, 3) void moe_gemm_kernel(
    const unsigned short* __restrict__ A,
    const float* __restrict__ W,
    const float* __restrict__ bias,
    const int* __restrict__ counts,
    const int* __restrict__ offs,
    const int* __restrict__ tab,
    const int* __restrict__ perm,
    void* __restrict__ outp) {
  const int te = tab[blockIdx.x];
  if (te < 0) return;
  const int e = te >> 24;
  const int m0 = ((te >> 16) & 255) << 7;
  const int n0 = ((te >> 8) & 255) << 7;
  const int kz = te & 255;
  const int cnt = counts[e];
  const int aoff = (MODE == 0) ? e * CAP : offs[e];
  const int hoff = offs[e];
  const int kstart = kz * (K / KSPLIT);
  constexpr int NSTEP = (K / KSPLIT) / 32;
  static_assert(NSTEP >= 4 && (NSTEP % 2) == 0, "NSTEP must be even >= 4");

  const int tid = threadIdx.x;
  const int lane = tid & 63;
  const int wave = tid >> 6;

  __shared__ __align__(16) unsigned short lA[2][4096];
  __shared__ __align__(16) unsigned short lB[2][4096];

  const int ra = tid & 127;
  const int qa = tid >> 7;
  const int arow = aoff + min(m0 + ra, cnt - 1);
  const unsigned short* asrc = A + (size_t)arow * K + kstart + qa * 8;
  const float* wsrc = W + (size_t)e * K * N + (size_t)(kstart + wave * 8) * N + n0 + lane;

  f32x4 acc[4][4] = {};
  const int wr = (wave >> 1) * 64;
  const int wc = (wave & 1) * 64;
  const int fr = lane & 15;
  const int fq = lane >> 4;

  short8 pA00, pA01, pA10, pA11;
  float pBa0[8], pBb0[8], pBa1[8], pBb1[8];

  pA00 = *(const short8*)(asrc);
  pA01 = *(const short8*)(asrc + 16);
#pragma unroll
  for (int j = 0; j < 8; ++j) {
    pBa0[j] = wsrc[(size_t)j * N];
    pBb0[j] = wsrc[(size_t)j * N + 64];
  }
  pA10 = *(const short8*)(asrc + 32);
  pA11 = *(const short8*)(asrc + 48);
  {
    const float* wp_ = wsrc + (size_t)32 * N;
#pragma unroll
    for (int j = 0; j < 8; ++j) {
      pBa1[j] = wp_[(size_t)j * N];
      pBb1[j] = wp_[(size_t)j * N + 64];
    }
  }
  *(short8*)&lA[0][qa * 1024 + ra * 8] = pA00;
  *(short8*)&lA[0][(qa + 2) * 1024 + ra * 8] = pA01;
  {
    short8 c0_, c1_;
#pragma unroll
    for (int j = 0; j < 8; ++j) {
      c0_[j] = (short)f2bf(pBa0[j]);
      c1_[j] = (short)f2bf(pBb0[j]);
    }
    *(short8*)&lB[0][wave * 1024 + lane * 8] = c0_;
    *(short8*)&lB[0][wave * 1024 + (lane + 64) * 8] = c1_;
  }
  asm volatile("s_waitcnt lgkmcnt(0)" ::: "memory");
  __builtin_amdgcn_s_barrier();
  asm volatile("" ::: "memory");

#define STEP_BODY(TV, CUR, NXT)                                                     \
  {                                                                                 \
    const int tv_ = (TV);                                                           \
    if (tv_ + 2 < NSTEP) {                                                          \
      const unsigned short* ap_ = asrc + (tv_ + 2) * 32;                            \
      pA##CUR##0 = *(const short8*)ap_;                                             \
      pA##CUR##1 = *(const short8*)(ap_ + 16);                                      \
      const float* wp_ = wsrc + (size_t)(tv_ + 2) * 32 * N;                         \
      _Pragma("unroll") for (int j = 0; j < 8; ++j) {                               \
        pBa##CUR[j] = wp_[(size_t)j * N];                                           \
        pBb##CUR[j] = wp_[(size_t)j * N + 64];                                      \
      }                                                                             \
    }                                                                               \
    if (tv_ + 1 < NSTEP) {                                                          \
      *(short8*)&lA[NXT][qa * 1024 + ra * 8] = pA##NXT##0;                          \
      *(short8*)&lA[NXT][(qa + 2) * 1024 + ra * 8] = pA##NXT##1;                    \
      short8 c0_, c1_;                                                              \
      _Pragma("unroll") for (int j = 0; j < 8; ++j) {                               \
        c0_[j] = (short)f2bf(pBa##NXT[j]);                                          \
        c1_[j] = (short)f2bf(pBb##NXT[j]);                                          \
      }                                                                             \
      *(short8*)&lB[NXT][wave * 1024 + lane * 8] = c0_;                             \
      *(short8*)&lB[NXT][wave * 1024 + (lane + 64) * 8] = c1_;                      \
    }                                                                               \
    short8 af_[4], bf_[4];                                                          \
    _Pragma("unroll") for (int m = 0; m < 4; ++m)                                   \
        af_[m] = *(const short8*)&lA[CUR][fq * 1024 + (wr + m * 16 + fr) * 8];      \
    _Pragma("unroll") for (int n = 0; n < 4; ++n)                                   \
        bf_[n] = *(const short8*)&lB[CUR][fq * 1024 + (wc + n * 16 + fr) * 8];      \
    __builtin_amdgcn_s_setprio(1);                                                  \
    _Pragma("unroll") for (int m = 0; m < 4; ++m)                                   \
        _Pragma("unroll") for (int n = 0; n < 4; ++n)                               \
            acc[m][n] =                                                             \
                __builtin_amdgcn_mfma_f32_16x16x32_bf16(af_[m], bf_[n],             \
                                                        acc[m][n], 0, 0, 0);        \
    __builtin_amdgcn_s_setprio(0);                                                  \
    asm volatile("s_waitcnt lgkmcnt(0)" ::: "memory");                              \
    __builtin_amdgcn_s_barrier();                                                   \
    asm volatile("" ::: "memory");                                                  \
  }

  for (int t = 0; t < NSTEP; t += 2) {
    STEP_BODY(t, 0, 1);
    STEP_BODY(t + 1, 1, 0);
  }
#undef STEP_BODY

  if (MODE == 0) {
    unsigned short* Hout = (unsigned short*)outp;
    float bv[4];
#pragma unroll
    for (int n = 0; n < 4; ++n) bv[n] = bias[e * N + n0 + wc + n * 16 + fr];
#pragma unroll
    for (int m = 0; m < 4; ++m) {
#pragma unroll
      for (int j = 0; j < 4; ++j) {
        int rg = m0 + wr + m * 16 + fq * 4 + j;
        if (rg < cnt) {
          size_t base = (size_t)(hoff + rg) * N;
#pragma unroll
          for (int n = 0; n < 4; ++n) {
            float hv = acc[m][n][j] + bv[n];
            hv = fmaxf(hv, 0.f);
            Hout[base + n0 + wc + n * 16 + fr] = f2bf(hv);
          }
        }
      }
    }
  } else {
    float* Out = (float*)outp;
#pragma unroll
    for (int m = 0; m < 4; ++m) {
#pragma unroll
      for (int j = 0; j < 4; ++j) {
        int rg = m0 + wr + m * 16 + fq * 4 + j;
        if (rg < cnt) {
          int token = perm[e * CAP + rg];
          size_t base = ((size_t)(token & (S_ - 1)) * B_ + (token >> 11)) * (size_t)D_;
#pragma unroll
          for (int n = 0; n < 4; ++n)
            atomicAdd(&Out[base + n0 + wc + n * 16 + fr], acc[m][n][j]);
        }
      }
    }
  }
}

extern "C" void kernel_launch(void* const* d_in, const int* in_sizes, int n_in,
                              void* d_out, int out_size, void* d_ws, size_t ws_size,
                              hipStream_t stream) {
  const float* x    = (const float*)d_in[0];
  const float* cent = (const float*)d_in[1];
  const float* lng  = (const float*)d_in[2];
  const float* lnb  = (const float*)d_in[3];
  const float* W1   = (const float*)d_in[4];
  const float* b1   = (const float*)d_in[5];
  const float* W2   = (const float*)d_in[6];
  const float* b2   = (const float*)d_in[7];
  float* out = (float*)d_out;

  char* ws = (char*)d_ws;
  int* counts = (int*)(ws + 0);
  int* offs   = (int*)(ws + 64);
  int* tabF1  = (int*)(ws + 4096);
  int* tabF2  = (int*)(ws + 12288);
  int* perm   = (int*)(ws + 20480);
  unsigned short* Xb = (unsigned short*)(ws + ((size_t)1 << 20));   // 16MB [E][CAP][D]
  unsigned short* H  = (unsigned short*)(ws + ((size_t)17 << 20));  // 32MB [T][F]
  unsigned short* WT = (unsigned short*)(ws + ((size_t)49 << 20));  // 64MB, reused W1T/W2T

  if (ws_size < ((size_t)1 << 26)) return;

  hipMemsetAsync(counts, 0, 64, stream);
  gate_ln_kernel<<<T_ / 4, 256, 0, stream>>>(x, cent, lng, lnb, b2, counts, perm, Xb, out);
  prefix_kernel<<<1, 256, 0, stream>>>(counts, offs, tabF1, tabF2);

  if (ws_size >= ((size_t)114 << 20)) {
    // PRIMARY: bf16-transposed weights + m97-style gload_lds GEMM
    // W1 [E][D][F] -> WT [E][F][D] bf16
    transpose_bf16_kernel<<<dim3(F_ / 64, D_ / 64, E_), 256, 0, stream>>>(W1, WT, D_, F_);
    moe_gemm_bt<D_, F_, 0, 1><<<NTABF, 256, 0, stream>>>(
        Xb, WT, b1, counts, offs, tabF1, perm, (void*)H);
    // W2 [E][F][D] -> WT [E][D][F] bf16
    transpose_bf16_kernel<<<dim3(D_ / 64, F_ / 64, E_), 256, 0, stream>>>(W2, WT, F_, D_);
    moe_gemm_bt<F_, D_, 1, 4><<<NTABF, 256, 0, stream>>>(
        H, WT, nullptr, counts, offs, tabF2, perm, (void*)out);
  } else {
    // FALLBACK (R7): fp32-W reg-staged GEMM
    moe_gemm_kernel<D_, F_, 0, 1><<<NTABF, 256, 0, stream>>>(
        Xb, W1, b1, counts, offs, tabF1, perm, (void*)H);
    moe_gemm_kernel<F_, D_, 1, 4><<<NTABF, 256, 0, stream>>>(
        H, W2, nullptr, counts, offs, tabF2, perm, (void*)out);
  }
}

// Round 9
// 368.894 us; speedup vs baseline: 1.2312x; 1.2312x over previous
//
#include <hip/hip_runtime.h>
#include <hip/hip_bf16.h>

#define E_ 8
#define D_ 1024
#define F_ 4096
#define S_ 2048
#define B_ 2
#define T_ 4096
#define CAP 1024
#define LN_EPS 1e-5f
#define NTABF 2048

typedef __attribute__((ext_vector_type(8))) short short8;
typedef __attribute__((ext_vector_type(4))) float f32x4;

__device__ __forceinline__ unsigned short f2bf(float f) {
  __hip_bfloat16 h = __float2bfloat16(f);
  return *reinterpret_cast<unsigned short*>(&h);
}

__device__ __forceinline__ void gload_lds16(const void* g, void* l) {
  __builtin_amdgcn_global_load_lds((const __attribute__((address_space(1))) void*)g,
                                   (__attribute__((address_space(3))) void*)l,
                                   16, 0, 0);
}

// ---------- fused gating + LN + bucket scatter + out init (x + b2[e]) ----------
__global__ __launch_bounds__(256) void gate_ln_kernel(
    const float* __restrict__ x, const float* __restrict__ cent,
    const float* __restrict__ g_, const float* __restrict__ bb_,
    const float* __restrict__ b2_,
    int* __restrict__ counts, int* __restrict__ perm,
    unsigned short* __restrict__ Xb, float* __restrict__ outp) {
  int token = blockIdx.x * 4 + (threadIdx.x >> 6);
  int lane = threadIdx.x & 63;
  int s = token & (S_ - 1), b = token >> 11;
  const float* xr = x + ((size_t)s * B_ + b) * D_;
  float* orow = outp + ((size_t)s * B_ + b) * D_;

  float v[16];
  float acc[E_];
#pragma unroll
  for (int e = 0; e < E_; ++e) acc[e] = 0.f;
  float sum = 0.f, sq = 0.f;
#pragma unroll
  for (int c = 0; c < 4; ++c) {
    f32x4 xv = *(const f32x4*)(xr + c * 256 + lane * 4);
    v[c * 4 + 0] = xv.x; v[c * 4 + 1] = xv.y; v[c * 4 + 2] = xv.z; v[c * 4 + 3] = xv.w;
    sum += xv.x + xv.y + xv.z + xv.w;
    sq += xv.x * xv.x + xv.y * xv.y + xv.z * xv.z + xv.w * xv.w;
#pragma unroll
    for (int e = 0; e < E_; ++e) {
      f32x4 cv = *(const f32x4*)(cent + e * D_ + c * 256 + lane * 4);
      acc[e] += xv.x * cv.x + xv.y * cv.y + xv.z * cv.z + xv.w * cv.w;
    }
  }
#pragma unroll
  for (int off = 32; off > 0; off >>= 1) {
    sum += __shfl_down(sum, off);
    sq += __shfl_down(sq, off);
#pragma unroll
    for (int e = 0; e < E_; ++e) acc[e] += __shfl_down(acc[e], off);
  }
  int best = 0, slot = 0;
  if (lane == 0) {
    float bv = acc[0];
#pragma unroll
    for (int e = 1; e < E_; ++e) if (acc[e] > bv) { bv = acc[e]; best = e; }
    slot = atomicAdd(&counts[best], 1);
    perm[best * CAP + slot] = token;
  }
  best = __shfl(best, 0); slot = __shfl(slot, 0);
  sum = __shfl(sum, 0); sq = __shfl(sq, 0);
  float mu = sum * (1.f / D_);
  float var = sq * (1.f / D_) - mu * mu;
  float rstd = rsqrtf(var + LN_EPS);
  int e = best;
  unsigned short* dst = Xb + (size_t)(e * CAP + slot) * D_;
#pragma unroll
  for (int c = 0; c < 4; ++c) {
    int d = c * 256 + lane * 4;
    f32x4 gv = *(const f32x4*)(g_ + e * D_ + d);
    f32x4 bv = *(const f32x4*)(bb_ + e * D_ + d);
    f32x4 b2v = *(const f32x4*)(b2_ + e * D_ + d);
    ushort4 o;
    o.x = f2bf((v[c * 4 + 0] - mu) * rstd * gv.x + bv.x);
    o.y = f2bf((v[c * 4 + 1] - mu) * rstd * gv.y + bv.y);
    o.z = f2bf((v[c * 4 + 2] - mu) * rstd * gv.z + bv.z);
    o.w = f2bf((v[c * 4 + 3] - mu) * rstd * gv.w + bv.w);
    *(ushort4*)(dst + d) = o;
    f32x4 oi;
    oi.x = v[c * 4 + 0] + b2v.x; oi.y = v[c * 4 + 1] + b2v.y;
    oi.z = v[c * 4 + 2] + b2v.z; oi.w = v[c * 4 + 3] + b2v.w;
    *(f32x4*)(orow + d) = oi;
  }
}

// ---------- prefix + XCD-grouped flat schedule tables ----------
__global__ __launch_bounds__(256) void prefix_kernel(
    const int* __restrict__ counts, int* __restrict__ offs,
    int* __restrict__ tabF1, int* __restrict__ tabF2) {
  __shared__ int q[8][256];
  __shared__ int ql[8];
  __shared__ int nb[E_];
  const int tid = threadIdx.x;
  if (tid == 0) {
    int s = 0;
    for (int e = 0; e < E_; ++e) {
      offs[e] = s;
      nb[e] = (counts[e] + 127) >> 7;
      s += counts[e];
    }
    offs[E_] = s;
    for (int x = 0; x < 8; ++x) ql[x] = 0;
    int g = 0;
    for (int n = 0; n < F_ / 128; ++n)
      for (int e = 0; e < E_; ++e) {
        int x = g & 7; ++g;
        for (int m = 0; m < nb[e]; ++m) q[x][ql[x]++] = (e << 24) | (m << 16) | (n << 8);
      }
  }
  __syncthreads();
  for (int i = tid; i < NTABF; i += 256) {
    int p = i >> 3, x = i & 7;
    tabF1[i] = (p < ql[x]) ? q[x][p] : -1;
  }
  __syncthreads();
  if (tid == 0) {
    for (int x = 0; x < 8; ++x) ql[x] = 0;
    int g = 0;
    for (int kz = 0; kz < 4; ++kz)
      for (int n = 0; n < D_ / 128; ++n)
        for (int e = 0; e < E_; ++e) {
          int x = g & 7; ++g;
          for (int m = 0; m < nb[e]; ++m)
            q[x][ql[x]++] = (e << 24) | (m << 16) | (n << 8) | kz;
        }
  }
  __syncthreads();
  for (int i = tid; i < NTABF; i += 256) {
    int p = i >> 3, x = i & 7;
    tabF2[i] = (p < ql[x]) ? q[x][p] : -1;
  }
}

// ---------- transpose + fp32->bf16: in [E][R][C] -> out [E][C][R], 16B writes ----------
__global__ __launch_bounds__(256) void transpose_bf16_kernel(const float* __restrict__ in,
    unsigned short* __restrict__ out, int R, int C) {
  __shared__ float tile[64][65];
  const float* src = in + (size_t)blockIdx.z * R * C;
  unsigned short* dst = out + (size_t)blockIdx.z * R * C;
  int c0 = blockIdx.x * 64, r0 = blockIdx.y * 64;
  int tid = threadIdx.x;
#pragma unroll
  for (int i = 0; i < 4; ++i) {
    int u = i * 256 + tid;
    int rr = u >> 4, c4 = (u & 15) * 4;
    f32x4 vv = *(const f32x4*)(src + (size_t)(r0 + rr) * C + c0 + c4);
    tile[rr][c4 + 0] = vv.x; tile[rr][c4 + 1] = vv.y;
    tile[rr][c4 + 2] = vv.z; tile[rr][c4 + 3] = vv.w;
  }
  __syncthreads();
#pragma unroll
  for (int i = 0; i < 2; ++i) {
    int u = i * 256 + tid;
    int orow = u >> 3;          // 0..63  (output row = original col c0+orow)
    int oc8 = (u & 7) * 8;      // 0..56  (output col block = original row r0+oc8)
    short8 o;
#pragma unroll
    for (int j = 0; j < 8; ++j) o[j] = (short)f2bf(tile[oc8 + j][orow]);
    *(short8*)(dst + (size_t)(c0 + orow) * R + r0 + oc8) = o;
  }
}

// ---------- PRIMARY grouped GEMM: BK=128, swizzled gload_lds, coalesced staging ----
// A[rows][K] bf16, BT[E][N][K] bf16. LDS tile [row][128k] with chunk^=(row&15) swizzle
// applied on BOTH global-source and ds_read (rule #21 both-sides).
// MODE 0: H = relu(A*W1 + b1) -> bf16 compact   MODE 1: atomicAdd into out (split-K)
template <int K, int N, int MODE, int KSPLIT>
__global__ __launch_bounds__(256) void moe_gemm_bk128(
    const unsigned short* __restrict__ A,
    const unsigned short* __restrict__ BT,
    const float* __restrict__ bias,
    const int* __restrict__ counts,
    const int* __restrict__ offs,
    const int* __restrict__ tab,
    const int* __restrict__ perm,
    void* __restrict__ outp) {
  const int te = tab[blockIdx.x];
  if (te < 0) return;
  const int e = te >> 24;
  const int m0 = ((te >> 16) & 255) << 7;
  const int n0 = ((te >> 8) & 255) << 7;
  const int kz = te & 255;
  const int cnt = counts[e];
  const int aoff = (MODE == 0) ? e * CAP : offs[e];
  const int hoff = offs[e];
  const int kstart = kz * (K / KSPLIT);
  constexpr int NSTEP = (K / KSPLIT) / 128;
  static_assert(NSTEP >= 1, "");

  const int tid = threadIdx.x;
  const int lane = tid & 63;
  const int wave = tid >> 6;

  __shared__ __align__(16) unsigned short lA[128 * 128];  // 32KB
  __shared__ __align__(16) unsigned short lB[128 * 128];  // 32KB

  // staging: instr i covers 16B cell c = i*256 + tid; row = c>>4, chunk = c&15.
  // row&15 == rbase for every i (i*16 keeps low 4 bits).
  const int rbase = tid >> 4;   // 0..15
  const int chunk = tid & 15;
  const int swz = ((chunk ^ rbase) << 4);  // byte offset within row's 256B window

  const char* aptr[8];
  const char* bptr[8];
#pragma unroll
  for (int i = 0; i < 8; ++i) {
    int row = i * 16 + rbase;
    int arow = aoff + min(m0 + row, cnt - 1);
    aptr[i] = (const char*)(A + (size_t)arow * K + kstart) + swz;
    bptr[i] = (const char*)(BT + ((size_t)e * N + n0 + row) * K + kstart) + swz;
  }

  f32x4 acc[4][4] = {};
  const int wr = (wave >> 1) * 64;
  const int wc = (wave & 1) * 64;
  const int fr = lane & 15;
  const int fq = lane >> 4;

  for (int t = 0; t < NSTEP; ++t) {
#pragma unroll
    for (int i = 0; i < 8; ++i) {
      gload_lds16(aptr[i], (char*)lA + i * 4096 + wave * 1024);
      gload_lds16(bptr[i], (char*)lB + i * 4096 + wave * 1024);
    }
    __syncthreads();  // drains vmcnt -> tiles ready
#pragma unroll
    for (int ks = 0; ks < 4; ++ks) {
      short8 af[4], bf4[4];
#pragma unroll
      for (int m = 0; m < 4; ++m) {
        int row = wr + m * 16 + fr;
        int kq = ks * 4 + fq;
        af[m] = *(const short8*)((const char*)lA + row * 256 + ((kq ^ (row & 15)) << 4));
      }
#pragma unroll
      for (int n = 0; n < 4; ++n) {
        int col = wc + n * 16 + fr;
        int kq = ks * 4 + fq;
        bf4[n] = *(const short8*)((const char*)lB + col * 256 + ((kq ^ (col & 15)) << 4));
      }
      __builtin_amdgcn_s_setprio(1);
#pragma unroll
      for (int m = 0; m < 4; ++m) {
#pragma unroll
        for (int n = 0; n < 4; ++n)
          acc[m][n] = __builtin_amdgcn_mfma_f32_16x16x32_bf16(af[m], bf4[n], acc[m][n], 0, 0, 0);
      }
      __builtin_amdgcn_s_setprio(0);
    }
    __syncthreads();  // tile consumed; safe to overwrite next step
#pragma unroll
    for (int i = 0; i < 8; ++i) { aptr[i] += 256; bptr[i] += 256; }
  }

  if (MODE == 0) {
    unsigned short* Hout = (unsigned short*)outp;
    float bv[4];
#pragma unroll
    for (int n = 0; n < 4; ++n) bv[n] = bias[e * N + n0 + wc + n * 16 + fr];
#pragma unroll
    for (int m = 0; m < 4; ++m) {
#pragma unroll
      for (int j = 0; j < 4; ++j) {
        int rg = m0 + wr + m * 16 + fq * 4 + j;
        if (rg < cnt) {
          size_t base = (size_t)(hoff + rg) * N;
#pragma unroll
          for (int n = 0; n < 4; ++n) {
            float hv = acc[m][n][j] + bv[n];
            hv = fmaxf(hv, 0.f);
            Hout[base + n0 + wc + n * 16 + fr] = f2bf(hv);
          }
        }
      }
    }
  } else {
    float* Out = (float*)outp;
#pragma unroll
    for (int m = 0; m < 4; ++m) {
#pragma unroll
      for (int j = 0; j < 4; ++j) {
        int rg = m0 + wr + m * 16 + fq * 4 + j;
        if (rg < cnt) {
          int token = perm[e * CAP + rg];
          size_t base = ((size_t)(token & (S_ - 1)) * B_ + (token >> 11)) * (size_t)D_;
#pragma unroll
          for (int n = 0; n < 4; ++n)
            atomicAdd(&Out[base + n0 + wc + n * 16 + fr], acc[m][n][j]);
        }
      }
    }
  }
}

// ---------- FALLBACK grouped GEMM (R7, fp32 W reg-staged): used when ws is small ----
template <int K, int N, int MODE, int KSPLIT>
__global__ __launch_bounds__(256, 3) void moe_gemm_kernel(
    const unsigned short* __restrict__ A,
    const float* __restrict__ W,
    const float* __restrict__ bias,
    const int* __restrict__ counts,
    const int* __restrict__ offs,
    const int* __restrict__ tab,
    const int* __restrict__ perm,
    void* __restrict__ outp) {
  const int te = tab[blockIdx.x];
  if (te < 0) return;
  const int e = te >> 24;
  const int m0 = ((te >> 16) & 255) << 7;
  const int n0 = ((te >> 8) & 255) << 7;
  const int kz = te & 255;
  const int cnt = counts[e];
  const int aoff = (MODE == 0) ? e * CAP : offs[e];
  const int hoff = offs[e];
  const int kstart = kz * (K / KSPLIT);
  constexpr int NSTEP = (K / KSPLIT) / 32;
  static_assert(NSTEP >= 4 && (NSTEP % 2) == 0, "NSTEP must be even >= 4");

  const int tid = threadIdx.x;
  const int lane = tid & 63;
  const int wave = tid >> 6;

  __shared__ __align__(16) unsigned short lA[2][4096];
  __shared__ __align__(16) unsigned short lB[2][4096];

  const int ra = tid & 127;
  const int qa = tid >> 7;
  const int arow = aoff + min(m0 + ra, cnt - 1);
  const unsigned short* asrc = A + (size_t)arow * K + kstart + qa * 8;
  const float* wsrc = W + (size_t)e * K * N + (size_t)(kstart + wave * 8) * N + n0 + lane;

  f32x4 acc[4][4] = {};
  const int wr = (wave >> 1) * 64;
  const int wc = (wave & 1) * 64;
  const int fr = lane & 15;
  const int fq = lane >> 4;

  short8 pA00, pA01, pA10, pA11;
  float pBa0[8], pBb0[8], pBa1[8], pBb1[8];

  pA00 = *(const short8*)(asrc);
  pA01 = *(const short8*)(asrc + 16);
#pragma unroll
  for (int j = 0; j < 8; ++j) {
    pBa0[j] = wsrc[(size_t)j * N];
    pBb0[j] = wsrc[(size_t)j * N + 64];
  }
  pA10 = *(const short8*)(asrc + 32);
  pA11 = *(const short8*)(asrc + 48);
  {
    const float* wp_ = wsrc + (size_t)32 * N;
#pragma unroll
    for (int j = 0; j < 8; ++j) {
      pBa1[j] = wp_[(size_t)j * N];
      pBb1[j] = wp_[(size_t)j * N + 64];
    }
  }
  *(short8*)&lA[0][qa * 1024 + ra * 8] = pA00;
  *(short8*)&lA[0][(qa + 2) * 1024 + ra * 8] = pA01;
  {
    short8 c0_, c1_;
#pragma unroll
    for (int j = 0; j < 8; ++j) {
      c0_[j] = (short)f2bf(pBa0[j]);
      c1_[j] = (short)f2bf(pBb0[j]);
    }
    *(short8*)&lB[0][wave * 1024 + lane * 8] = c0_;
    *(short8*)&lB[0][wave * 1024 + (lane + 64) * 8] = c1_;
  }
  asm volatile("s_waitcnt lgkmcnt(0)" ::: "memory");
  __builtin_amdgcn_s_barrier();
  asm volatile("" ::: "memory");

#define STEP_BODY(TV, CUR, NXT)                                                     \
  {                                                                                 \
    const int tv_ = (TV);                                                           \
    if (tv_ + 2 < NSTEP) {                                                          \
      const unsigned short* ap_ = asrc + (tv_ + 2) * 32;                            \
      pA##CUR##0 = *(const short8*)ap_;                                             \
      pA##CUR##1 = *(const short8*)(ap_ + 16);                                      \
      const float* wp_ = wsrc + (size_t)(tv_ + 2) * 32 * N;                         \
      _Pragma("unroll") for (int j = 0; j < 8; ++j) {                               \
        pBa##CUR[j] = wp_[(size_t)j * N];                                           \
        pBb##CUR[j] = wp_[(size_t)j * N + 64];                                      \
      }                                                                             \
    }                                                                               \
    if (tv_ + 1 < NSTEP) {                                                          \
      *(short8*)&lA[NXT][qa * 1024 + ra * 8] = pA##NXT##0;                          \
      *(short8*)&lA[NXT][(qa + 2) * 1024 + ra * 8] = pA##NXT##1;                    \
      short8 c0_, c1_;                                                              \
      _Pragma("unroll") for (int j = 0; j < 8; ++j) {                               \
        c0_[j] = (short)f2bf(pBa##NXT[j]);                                          \
        c1_[j] = (short)f2bf(pBb##NXT[j]);                                          \
      }                                                                             \
      *(short8*)&lB[NXT][wave * 1024 + lane * 8] = c0_;                             \
      *(short8*)&lB[NXT][wave * 1024 + (lane + 64) * 8] = c1_;                      \
    }                                                                               \
    short8 af_[4], bf_[4];                                                          \
    _Pragma("unroll") for (int m = 0; m < 4; ++m)                                   \
        af_[m] = *(const short8*)&lA[CUR][fq * 1024 + (wr + m * 16 + fr) * 8];      \
    _Pragma("unroll") for (int n = 0; n < 4; ++n)                                   \
        bf_[n] = *(const short8*)&lB[CUR][fq * 1024 + (wc + n * 16 + fr) * 8];      \
    __builtin_amdgcn_s_setprio(1);                                                  \
    _Pragma("unroll") for (int m = 0; m < 4; ++m)                                   \
        _Pragma("unroll") for (int n = 0; n < 4; ++n)                               \
            acc[m][n] =                                                             \
                __builtin_amdgcn_mfma_f32_16x16x32_bf16(af_[m], bf_[n],             \
                                                        acc[m][n], 0, 0, 0);        \
    __builtin_amdgcn_s_setprio(0);                                                  \
    asm volatile("s_waitcnt lgkmcnt(0)" ::: "memory");                              \
    __builtin_amdgcn_s_barrier();                                                   \
    asm volatile("" ::: "memory");                                                  \
  }

  for (int t = 0; t < NSTEP; t += 2) {
    STEP_BODY(t, 0, 1);
    STEP_BODY(t + 1, 1, 0);
  }
#undef STEP_BODY

  if (MODE == 0) {
    unsigned short* Hout = (unsigned short*)outp;
    float bv[4];
#pragma unroll
    for (int n = 0; n < 4; ++n) bv[n] = bias[e * N + n0 + wc + n * 16 + fr];
#pragma unroll
    for (int m = 0; m < 4; ++m) {
#pragma unroll
      for (int j = 0; j < 4; ++j) {
        int rg = m0 + wr + m * 16 + fq * 4 + j;
        if (rg < cnt) {
          size_t base = (size_t)(hoff + rg) * N;
#pragma unroll
          for (int n = 0; n < 4; ++n) {
            float hv = acc[m][n][j] + bv[n];
            hv = fmaxf(hv, 0.f);
            Hout[base + n0 + wc + n * 16 + fr] = f2bf(hv);
          }
        }
      }
    }
  } else {
    float* Out = (float*)outp;
#pragma unroll
    for (int m = 0; m < 4; ++m) {
#pragma unroll
      for (int j = 0; j < 4; ++j) {
        int rg = m0 + wr + m * 16 + fq * 4 + j;
        if (rg < cnt) {
          int token = perm[e * CAP + rg];
          size_t base = ((size_t)(token & (S_ - 1)) * B_ + (token >> 11)) * (size_t)D_;
#pragma unroll
          for (int n = 0; n < 4; ++n)
            atomicAdd(&Out[base + n0 + wc + n * 16 + fr], acc[m][n][j]);
        }
      }
    }
  }
}

extern "C" void kernel_launch(void* const* d_in, const int* in_sizes, int n_in,
                              void* d_out, int out_size, void* d_ws, size_t ws_size,
                              hipStream_t stream) {
  const float* x    = (const float*)d_in[0];
  const float* cent = (const float*)d_in[1];
  const float* lng  = (const float*)d_in[2];
  const float* lnb  = (const float*)d_in[3];
  const float* W1   = (const float*)d_in[4];
  const float* b1   = (const float*)d_in[5];
  const float* W2   = (const float*)d_in[6];
  const float* b2   = (const float*)d_in[7];
  float* out = (float*)d_out;

  char* ws = (char*)d_ws;
  int* counts = (int*)(ws + 0);
  int* offs   = (int*)(ws + 64);
  int* tabF1  = (int*)(ws + 4096);
  int* tabF2  = (int*)(ws + 12288);
  int* perm   = (int*)(ws + 20480);
  unsigned short* Xb = (unsigned short*)(ws + ((size_t)1 << 20));   // 16MB [E][CAP][D]
  unsigned short* H  = (unsigned short*)(ws + ((size_t)17 << 20));  // 32MB [T][F]
  unsigned short* WT = (unsigned short*)(ws + ((size_t)49 << 20));  // 64MB, reused W1T/W2T

  if (ws_size < ((size_t)1 << 26)) return;

  hipMemsetAsync(counts, 0, 64, stream);
  gate_ln_kernel<<<T_ / 4, 256, 0, stream>>>(x, cent, lng, lnb, b2, counts, perm, Xb, out);
  prefix_kernel<<<1, 256, 0, stream>>>(counts, offs, tabF1, tabF2);

  if (ws_size >= ((size_t)114 << 20)) {
    // PRIMARY: bf16-transposed weights + BK=128 swizzled gload_lds GEMM
    transpose_bf16_kernel<<<dim3(F_ / 64, D_ / 64, E_), 256, 0, stream>>>(W1, WT, D_, F_);
    moe_gemm_bk128<D_, F_, 0, 1><<<NTABF, 256, 0, stream>>>(
        Xb, WT, b1, counts, offs, tabF1, perm, (void*)H);
    transpose_bf16_kernel<<<dim3(D_ / 64, F_ / 64, E_), 256, 0, stream>>>(W2, WT, F_, D_);
    moe_gemm_bk128<F_, D_, 1, 4><<<NTABF, 256, 0, stream>>>(
        H, WT, nullptr, counts, offs, tabF2, perm, (void*)out);
  } else {
    // FALLBACK (R7): fp32-W reg-staged GEMM
    moe_gemm_kernel<D_, F_, 0, 1><<<NTABF, 256, 0, stream>>>(
        Xb, W1, b1, counts, offs, tabF1, perm, (void*)H);
    moe_gemm_kernel<F_, D_, 1, 4><<<NTABF, 256, 0, stream>>>(
        H, W2, nullptr, counts, offs, tabF2, perm, (void*)out);
  }
}

// Round 10
// 359.937 us; speedup vs baseline: 1.2618x; 1.0249x over previous
//
#include <hip/hip_runtime.h>
#include <hip/hip_bf16.h>

#define E_ 8
#define D_ 1024
#define F_ 4096
#define S_ 2048
#define B_ 2
#define T_ 4096
#define CAP 1024
#define LN_EPS 1e-5f
#define NTABF 2048

typedef __attribute__((ext_vector_type(8))) short short8;
typedef __attribute__((ext_vector_type(4))) float f32x4;

__device__ __forceinline__ unsigned short f2bf(float f) {
  __hip_bfloat16 h = __float2bfloat16(f);
  return *reinterpret_cast<unsigned short*>(&h);
}

__device__ __forceinline__ void gload_lds16(const void* g, void* l) {
  __builtin_amdgcn_global_load_lds((const __attribute__((address_space(1))) void*)g,
                                   (__attribute__((address_space(3))) void*)l,
                                   16, 0, 0);
}

// ---------- fused gating + LN + bucket scatter + out init (x + b2[e]) ----------
__global__ __launch_bounds__(256) void gate_ln_kernel(
    const float* __restrict__ x, const float* __restrict__ cent,
    const float* __restrict__ g_, const float* __restrict__ bb_,
    const float* __restrict__ b2_,
    int* __restrict__ counts, int* __restrict__ perm,
    unsigned short* __restrict__ Xb, float* __restrict__ outp) {
  int token = blockIdx.x * 4 + (threadIdx.x >> 6);
  int lane = threadIdx.x & 63;
  int s = token & (S_ - 1), b = token >> 11;
  const float* xr = x + ((size_t)s * B_ + b) * D_;
  float* orow = outp + ((size_t)s * B_ + b) * D_;

  float v[16];
  float acc[E_];
#pragma unroll
  for (int e = 0; e < E_; ++e) acc[e] = 0.f;
  float sum = 0.f, sq = 0.f;
#pragma unroll
  for (int c = 0; c < 4; ++c) {
    f32x4 xv = *(const f32x4*)(xr + c * 256 + lane * 4);
    v[c * 4 + 0] = xv.x; v[c * 4 + 1] = xv.y; v[c * 4 + 2] = xv.z; v[c * 4 + 3] = xv.w;
    sum += xv.x + xv.y + xv.z + xv.w;
    sq += xv.x * xv.x + xv.y * xv.y + xv.z * xv.z + xv.w * xv.w;
#pragma unroll
    for (int e = 0; e < E_; ++e) {
      f32x4 cv = *(const f32x4*)(cent + e * D_ + c * 256 + lane * 4);
      acc[e] += xv.x * cv.x + xv.y * cv.y + xv.z * cv.z + xv.w * cv.w;
    }
  }
#pragma unroll
  for (int off = 32; off > 0; off >>= 1) {
    sum += __shfl_down(sum, off);
    sq += __shfl_down(sq, off);
#pragma unroll
    for (int e = 0; e < E_; ++e) acc[e] += __shfl_down(acc[e], off);
  }
  int best = 0, slot = 0;
  if (lane == 0) {
    float bv = acc[0];
#pragma unroll
    for (int e = 1; e < E_; ++e) if (acc[e] > bv) { bv = acc[e]; best = e; }
    slot = atomicAdd(&counts[best], 1);
    perm[best * CAP + slot] = token;
  }
  best = __shfl(best, 0); slot = __shfl(slot, 0);
  sum = __shfl(sum, 0); sq = __shfl(sq, 0);
  float mu = sum * (1.f / D_);
  float var = sq * (1.f / D_) - mu * mu;
  float rstd = rsqrtf(var + LN_EPS);
  int e = best;
  unsigned short* dst = Xb + (size_t)(e * CAP + slot) * D_;
#pragma unroll
  for (int c = 0; c < 4; ++c) {
    int d = c * 256 + lane * 4;
    f32x4 gv = *(const f32x4*)(g_ + e * D_ + d);
    f32x4 bv = *(const f32x4*)(bb_ + e * D_ + d);
    f32x4 b2v = *(const f32x4*)(b2_ + e * D_ + d);
    ushort4 o;
    o.x = f2bf((v[c * 4 + 0] - mu) * rstd * gv.x + bv.x);
    o.y = f2bf((v[c * 4 + 1] - mu) * rstd * gv.y + bv.y);
    o.z = f2bf((v[c * 4 + 2] - mu) * rstd * gv.z + bv.z);
    o.w = f2bf((v[c * 4 + 3] - mu) * rstd * gv.w + bv.w);
    *(ushort4*)(dst + d) = o;
    f32x4 oi;
    oi.x = v[c * 4 + 0] + b2v.x; oi.y = v[c * 4 + 1] + b2v.y;
    oi.z = v[c * 4 + 2] + b2v.z; oi.w = v[c * 4 + 3] + b2v.w;
    *(f32x4*)(orow + d) = oi;
  }
}

// ---------- prefix + XCD-grouped (expert-pinned) 256-tile schedule tables ----------
// entry: (e<<24)|(m<<16)|(n<<8)|kz ; -1 empty. Table idx i -> XCD i&7.
// Expert e always maps to XCD e; m-blocks of one (e,n[,kz]) group are adjacent.
__global__ __launch_bounds__(256) void prefix_kernel(
    const int* __restrict__ counts, int* __restrict__ offs,
    int* __restrict__ tabF1, int* __restrict__ tabF2) {
  __shared__ int q[8][256];
  __shared__ int ql[8];
  __shared__ int nb[E_];
  const int tid = threadIdx.x;
  if (tid == 0) {
    int s = 0;
    for (int e = 0; e < E_; ++e) {
      offs[e] = s;
      nb[e] = (counts[e] + 255) >> 8;
      s += counts[e];
    }
    offs[E_] = s;
    for (int x = 0; x < 8; ++x) ql[x] = 0;
    int g = 0;
    for (int n = 0; n < F_ / 256; ++n)
      for (int e = 0; e < E_; ++e) {
        int x = g & 7; ++g;
        for (int m = 0; m < nb[e]; ++m) q[x][ql[x]++] = (e << 24) | (m << 16) | (n << 8);
      }
  }
  __syncthreads();
  for (int i = tid; i < NTABF; i += 256) {
    int p = i >> 3, x = i & 7;
    tabF1[i] = (p < ql[x]) ? q[x][p] : -1;
  }
  __syncthreads();
  if (tid == 0) {
    for (int x = 0; x < 8; ++x) ql[x] = 0;
    int g = 0;
    for (int kz = 0; kz < 4; ++kz)
      for (int n = 0; n < D_ / 256; ++n)
        for (int e = 0; e < E_; ++e) {
          int x = g & 7; ++g;
          for (int m = 0; m < nb[e]; ++m)
            q[x][ql[x]++] = (e << 24) | (m << 16) | (n << 8) | kz;
        }
  }
  __syncthreads();
  for (int i = tid; i < NTABF; i += 256) {
    int p = i >> 3, x = i & 7;
    tabF2[i] = (p < ql[x]) ? q[x][p] : -1;
  }
}

// ---------- transpose + fp32->bf16: in [E][R][C] -> out [E][C][R], 16B writes ----------
__global__ __launch_bounds__(256) void transpose_bf16_kernel(const float* __restrict__ in,
    unsigned short* __restrict__ out, int R, int C) {
  __shared__ float tile[64][65];
  const float* src = in + (size_t)blockIdx.z * R * C;
  unsigned short* dst = out + (size_t)blockIdx.z * R * C;
  int c0 = blockIdx.x * 64, r0 = blockIdx.y * 64;
  int tid = threadIdx.x;
#pragma unroll
  for (int i = 0; i < 4; ++i) {
    int u = i * 256 + tid;
    int rr = u >> 4, c4 = (u & 15) * 4;
    f32x4 vv = *(const f32x4*)(src + (size_t)(r0 + rr) * C + c0 + c4);
    tile[rr][c4 + 0] = vv.x; tile[rr][c4 + 1] = vv.y;
    tile[rr][c4 + 2] = vv.z; tile[rr][c4 + 3] = vv.w;
  }
  __syncthreads();
#pragma unroll
  for (int i = 0; i < 2; ++i) {
    int u = i * 256 + tid;
    int orow = u >> 3;
    int oc8 = (u & 7) * 8;
    short8 o;
#pragma unroll
    for (int j = 0; j < 8; ++j) o[j] = (short)f2bf(tile[oc8 + j][orow]);
    *(short8*)(dst + (size_t)(c0 + orow) * R + r0 + oc8) = o;
  }
}

// ---------- grouped GEMM: 256x256 tile, BK=128, swizzled gload_lds staging ----------
// A[rows][K] bf16, BT[E][N][K] bf16. LDS [row][256B k-window], chunk ^= row&15 on
// both global-source and ds_read sides (rule #21). 512 thr / 8 waves (2M x 4N).
// MODE 0: H = relu(A*W1 + b1) -> bf16 compact (nontemporal)
// MODE 1: atomicAdd into out (split-K)
template <int K, int N, int MODE, int KSPLIT>
__global__ __launch_bounds__(512) void moe_gemm_256(
    const unsigned short* __restrict__ A,
    const unsigned short* __restrict__ BT,
    const float* __restrict__ bias,
    const int* __restrict__ counts,
    const int* __restrict__ offs,
    const int* __restrict__ tab,
    const int* __restrict__ perm,
    void* __restrict__ outp) {
  const int te = tab[blockIdx.x];
  if (te < 0) return;
  const int e = te >> 24;
  const int m0 = ((te >> 16) & 255) << 8;
  const int n0 = ((te >> 8) & 255) << 8;
  const int kz = te & 255;
  const int cnt = counts[e];
  const int aoff = (MODE == 0) ? e * CAP : offs[e];
  const int hoff = offs[e];
  const int kstart = kz * (K / KSPLIT);
  constexpr int NSTEP = (K / KSPLIT) / 128;
  static_assert(NSTEP >= 1, "");

  const int tid = threadIdx.x;
  const int lane = tid & 63;
  const int wave = tid >> 6;   // 0..7

  __shared__ __align__(16) unsigned short lA[256 * 128];  // 64KB
  __shared__ __align__(16) unsigned short lB[256 * 128];  // 64KB

  // staging: instr i covers 16B cell c = i*512 + tid; row = c>>4 = i*32 + (tid>>4),
  // chunk-slot = tid&15. Global source chunk = slot ^ (row&15)  (row&15 = rbase&15).
  const int rbase = tid >> 4;   // 0..31
  const int chunk = tid & 15;
  const int swz = ((chunk ^ (rbase & 15)) << 4);  // byte offset in row's 256B window

  const char* aptr[8];
#pragma unroll
  for (int i = 0; i < 8; ++i) {
    int row = i * 32 + rbase;
    int arow = aoff + min(m0 + row, cnt - 1);
    aptr[i] = (const char*)(A + (size_t)arow * K + kstart) + swz;
  }
  const char* bptr = (const char*)(BT + ((size_t)e * N + n0 + rbase) * K + kstart) + swz;

  f32x4 acc[8][4] = {};
  const int wr = wave >> 2;    // 0..1 (M half)
  const int wc = wave & 3;     // 0..3 (N quarter)
  const int fr = lane & 15;
  const int fq = lane >> 4;

  for (int t = 0; t < NSTEP; ++t) {
#pragma unroll
    for (int i = 0; i < 8; ++i) {
      gload_lds16(aptr[i], (char*)lA + i * 8192 + wave * 1024);
      gload_lds16(bptr + (size_t)i * (32 * K * 2), (char*)lB + i * 8192 + wave * 1024);
    }
    __syncthreads();  // drains vmcnt -> tiles ready
#pragma unroll
    for (int ks = 0; ks < 4; ++ks) {
      const int kq = ks * 4 + fq;
      short8 af[8], bf4[4];
#pragma unroll
      for (int m = 0; m < 8; ++m) {
        int row = wr * 128 + m * 16 + fr;
        af[m] = *(const short8*)((const char*)lA + row * 256 + ((kq ^ (row & 15)) << 4));
      }
#pragma unroll
      for (int n = 0; n < 4; ++n) {
        int col = wc * 64 + n * 16 + fr;
        bf4[n] = *(const short8*)((const char*)lB + col * 256 + ((kq ^ (col & 15)) << 4));
      }
      __builtin_amdgcn_s_setprio(1);
#pragma unroll
      for (int m = 0; m < 8; ++m) {
#pragma unroll
        for (int n = 0; n < 4; ++n)
          acc[m][n] = __builtin_amdgcn_mfma_f32_16x16x32_bf16(af[m], bf4[n], acc[m][n], 0, 0, 0);
      }
      __builtin_amdgcn_s_setprio(0);
    }
    __syncthreads();  // tile consumed; safe to overwrite
#pragma unroll
    for (int i = 0; i < 8; ++i) aptr[i] += 256;
    bptr += 256;
  }

  if (MODE == 0) {
    unsigned short* Hout = (unsigned short*)outp;
    float bv[4];
#pragma unroll
    for (int n = 0; n < 4; ++n) bv[n] = bias[e * N + n0 + wc * 64 + n * 16 + fr];
#pragma unroll
    for (int m = 0; m < 8; ++m) {
#pragma unroll
      for (int j = 0; j < 4; ++j) {
        int rg = m0 + wr * 128 + m * 16 + fq * 4 + j;
        if (rg < cnt) {
          size_t base = (size_t)(hoff + rg) * N;
#pragma unroll
          for (int n = 0; n < 4; ++n) {
            float hv = acc[m][n][j] + bv[n];
            hv = fmaxf(hv, 0.f);
            __builtin_nontemporal_store(f2bf(hv), &Hout[base + n0 + wc * 64 + n * 16 + fr]);
          }
        }
      }
    }
  } else {
    float* Out = (float*)outp;
#pragma unroll
    for (int m = 0; m < 8; ++m) {
#pragma unroll
      for (int j = 0; j < 4; ++j) {
        int rg = m0 + wr * 128 + m * 16 + fq * 4 + j;
        if (rg < cnt) {
          int token = perm[e * CAP + rg];
          size_t base = ((size_t)(token & (S_ - 1)) * B_ + (token >> 11)) * (size_t)D_;
#pragma unroll
          for (int n = 0; n < 4; ++n)
            atomicAdd(&Out[base + n0 + wc * 64 + n * 16 + fr], acc[m][n][j]);
        }
      }
    }
  }
}

extern "C" void kernel_launch(void* const* d_in, const int* in_sizes, int n_in,
                              void* d_out, int out_size, void* d_ws, size_t ws_size,
                              hipStream_t stream) {
  const float* x    = (const float*)d_in[0];
  const float* cent = (const float*)d_in[1];
  const float* lng  = (const float*)d_in[2];
  const float* lnb  = (const float*)d_in[3];
  const float* W1   = (const float*)d_in[4];
  const float* b1   = (const float*)d_in[5];
  const float* W2   = (const float*)d_in[6];
  const float* b2   = (const float*)d_in[7];
  float* out = (float*)d_out;

  char* ws = (char*)d_ws;
  int* counts = (int*)(ws + 0);
  int* offs   = (int*)(ws + 64);
  int* tabF1  = (int*)(ws + 4096);
  int* tabF2  = (int*)(ws + 12288);
  int* perm   = (int*)(ws + 20480);
  unsigned short* Xb = (unsigned short*)(ws + ((size_t)1 << 20));   // 16MB [E][CAP][D]
  unsigned short* H  = (unsigned short*)(ws + ((size_t)17 << 20));  // 32MB [T][F] compact
  unsigned short* WT = (unsigned short*)(ws + ((size_t)49 << 20));  // 64MB, reused W1T/W2T

  if (ws_size < ((size_t)114 << 20)) return;  // need 114MB scratch (proven available)

  hipMemsetAsync(counts, 0, 64, stream);
  gate_ln_kernel<<<T_ / 4, 256, 0, stream>>>(x, cent, lng, lnb, b2, counts, perm, Xb, out);
  prefix_kernel<<<1, 256, 0, stream>>>(counts, offs, tabF1, tabF2);

  // W1 [E][D][F] -> WT [E][F][D] bf16
  transpose_bf16_kernel<<<dim3(F_ / 64, D_ / 64, E_), 256, 0, stream>>>(W1, WT, D_, F_);
  // FF1: H = relu(Xb * W1 + b1)
  moe_gemm_256<D_, F_, 0, 1><<<NTABF, 512, 0, stream>>>(
      Xb, WT, b1, counts, offs, tabF1, perm, (void*)H);
  // W2 [E][F][D] -> WT [E][D][F] bf16
  transpose_bf16_kernel<<<dim3(D_ / 64, F_ / 64, E_), 256, 0, stream>>>(W2, WT, F_, D_);
  // FF2: out += H * W2 (split-K=4; out pre-initialized with x + b2)
  moe_gemm_256<F_, D_, 1, 4><<<NTABF, 512, 0, stream>>>(
      H, WT, nullptr, counts, offs, tabF2, perm, (void*)out);
}